// Round 12
// baseline (239.253 us; speedup 1.0000x reference)
//
#include <hip/hip_runtime.h>
#include <stdint.h>

// Per-row top-K magnitude masking, exact.
// x: (4096 rows, 8192 cols) fp32. K = 819. One 256-thread block per row, row
// held in registers (8 x uint4 / thread). Exact radix select on the 31-bit
// abs bit pattern in 3 phases: 11 bits (2048 bins, u16-packed, 2 copies),
// 10 bits, 10 bits (u32, 1 copy).
//
// R12 = R6 skeleton (the measured 83us floor; 12 structures land 83-97)
// + EARLY SPLIT STORE. Every prior rev serialized the full 32KB store
// behind the complete 3-phase threshold. But phase 1 already decides 97.5%
// of elements: key>>20 > d1 -> certainly kept, < d1 -> certainly zero;
// only the ~200 bin-d1 elements await d2/d3. So: issue the full store right
// after phase 1 with the provisional rule (key >= d1<<20 keeps), let it
// drain under phases 2/3 (pure LDS/VALU, no VMEM contention), then after
// the exact thr do ONE s_waitcnt vmcnt(0) (provisional store is ~retired by
// then; also guarantees same-address write ordering) and a tiny scattered
// correction: zero the pending elements with key in [d1<<20, thr). Each
// element is corrected by the thread that wrote it.

constexpr int NCOLS = 8192;
constexpr int TPB   = 256;
constexpr int V4    = NCOLS / 4;   // 2048 uint4 per row
constexpr int VPT   = V4 / TPB;    // 8 uint4 per thread

constexpr int PAD = 8;             // words between histogram copies (bank shift)
constexpr int W1  = 1024;          // phase-1 words per copy (2048 bins, u16-packed)
constexpr int S1  = W1 + PAD;      // 1032
constexpr int C1  = 2;             // phase-1 copies (2 waves/copy)
constexpr int B2  = 1024;          // phase-2/3 bins (u32, single copy)
constexpr int S2  = B2 + PAD;      // 1032
constexpr int HW  = (C1 * S1 > S2) ? C1 * S1 : S2;   // 2064 words = 8256 B

struct Shared {
  uint32_t hist[HW];
  uint32_t wavesum[4];
  uint32_t digit;
  uint32_t rem;
};

// Suffix-scan + winner pick shared by all phases. hb[] are this thread's bin
// counts over bins [tid*BPT, tid*BPT+BPT). S(b) = #candidates with digit >= b.
// Winner: S(b) >= rem && S(b+1) < rem (unique). Updates rem to rank in bin.
template <int BPT>
__device__ __forceinline__ uint32_t pick_winner(Shared& sh, const uint32_t (&hb)[BPT],
                                                uint32_t& rem, int tid, int lane, int wave) {
  uint32_t L = 0;
#pragma unroll
  for (int j = 0; j < BPT; ++j) L += hb[j];

  // Wave-level inclusive suffix scan of L (no barriers).
  uint32_t suf = L;
#pragma unroll
  for (int off = 1; off < 64; off <<= 1) {
    uint32_t o = __shfl_down(suf, off, 64);
    suf += (lane + off < 64) ? o : 0u;
  }
  if (lane == 0) sh.wavesum[wave] = suf;   // wave total
  __syncthreads();
  uint32_t addw = 0;
#pragma unroll
  for (int w = 0; w < 4; ++w) addw += (w > wave) ? sh.wavesum[w] : 0u;
  suf += addw;  // suffix count starting at this thread's first bin

  uint32_t s = suf - L;                    // S at bin (tid+1)*BPT
#pragma unroll
  for (int j = BPT - 1; j >= 0; --j) {
    uint32_t snext = s;                    // S(bin+1)
    s += hb[j];                            // S(bin)
    if (s >= rem && snext < rem) {
      sh.digit = (uint32_t)(tid * BPT + j);
      sh.rem = rem - snext;
    }
  }
  __syncthreads();
  uint32_t d = sh.digit;
  rem = sh.rem;
  // No trailing barrier needed: next phase's first barrier (after zeroing)
  // orders these reads before any write to sh.digit/sh.rem/wavesum, and the
  // zeroing only touches hist[], whose reads completed before the wavesum
  // barrier above.
  return d;
}

// Phase 1: 11-bit digit (bits 30..20), 2048 bins, u16-packed, 2 copies.
// Packing: bin b -> word (b & 1023), halfword (b >> 10); the two halves of a
// word differ by 128 in the exponent field so they are never both hot, and
// per-copy per-half counts <= 4096 < 2^16.
__device__ __forceinline__ uint32_t phase1(Shared& sh, const uint4 (&v)[VPT],
                                           uint32_t& rem, int tid, int lane, int wave) {
  uint4* hz = (uint4*)sh.hist;
  constexpr int ZW4 = (C1 * S1) / 4;       // 516
  for (int i = tid; i < ZW4; i += TPB) hz[i] = make_uint4(0u, 0u, 0u, 0u);
  __syncthreads();

  uint32_t* h = &sh.hist[(wave >> 1) * S1];
#pragma unroll
  for (int i = 0; i < VPT; ++i) {
    uint32_t a[4] = {v[i].x, v[i].y, v[i].z, v[i].w};
#pragma unroll
    for (int j = 0; j < 4; ++j) {
      uint32_t d = (a[j] & 0x7fffffffu) >> 20;          // 11-bit digit
      atomicAdd(&h[d & (W1 - 1)], 1u << ((d >> 10) << 4));
    }
  }
  __syncthreads();

  // Combine copies; thread owns bins [tid*8, tid*8+8), all in one halfword.
  constexpr int BPT = 2048 / TPB;          // 8
  uint32_t hb[BPT];
#pragma unroll
  for (int j = 0; j < BPT; ++j) hb[j] = 0;
  const int wbase = (tid & 127) * BPT;     // word base within a copy
  const int shift = (tid >> 7) << 4;       // low half (tid<128) / high half
#pragma unroll
  for (int c = 0; c < C1; ++c) {
    const uint4* hp = (const uint4*)&sh.hist[c * S1 + wbase];
#pragma unroll
    for (int q = 0; q < BPT / 4; ++q) {
      uint4 t = hp[q];
      hb[4 * q + 0] += (t.x >> shift) & 0xffffu;
      hb[4 * q + 1] += (t.y >> shift) & 0xffffu;
      hb[4 * q + 2] += (t.z >> shift) & 0xffffu;
      hb[4 * q + 3] += (t.w >> shift) & 0xffffu;
    }
  }
  return pick_winner<BPT>(sh, hb, rem, tid, lane, wave);
}

// Phases 2/3: 10-bit digit, 1024 u32 bins, single copy (few candidates).
__device__ __forceinline__ uint32_t phase23(Shared& sh, const uint4 (&v)[VPT],
                                            int dshift, int cshift, uint32_t cprefix,
                                            uint32_t& rem, int tid, int lane, int wave) {
  uint4* hz = (uint4*)sh.hist;
  constexpr int ZW4 = S2 / 4;              // 258
  for (int i = tid; i < ZW4; i += TPB) hz[i] = make_uint4(0u, 0u, 0u, 0u);
  __syncthreads();

#pragma unroll
  for (int i = 0; i < VPT; ++i) {
    uint32_t a[4] = {v[i].x, v[i].y, v[i].z, v[i].w};
#pragma unroll
    for (int j = 0; j < 4; ++j) {
      uint32_t key = a[j] & 0x7fffffffu;
      if ((key >> cshift) == cprefix)
        atomicAdd(&sh.hist[(key >> dshift) & (B2 - 1)], 1u);
    }
  }
  __syncthreads();

  constexpr int BPT = B2 / TPB;            // 4
  uint32_t hb[BPT];
  const uint4 t = *(const uint4*)&sh.hist[tid * BPT];
  hb[0] = t.x; hb[1] = t.y; hb[2] = t.z; hb[3] = t.w;
  return pick_winner<BPT>(sh, hb, rem, tid, lane, wave);
}

__global__ __launch_bounds__(TPB, 4) void topk_row_kernel(const float* __restrict__ x,
                                                          float* __restrict__ out,
                                                          int K) {
  __shared__ Shared sh;
  const int row  = blockIdx.x;
  const int tid  = threadIdx.x;
  const int lane = tid & 63;
  const int wave = tid >> 6;

  const uint4* xr = (const uint4*)(x) + (size_t)row * V4;
  uint4 v[VPT];
#pragma unroll
  for (int i = 0; i < VPT; ++i) v[i] = xr[tid + i * TPB];

  // Pin the row in the register file (forbids remat; AGPR parking proven
  // cheap in R4-R6). Zero instructions.
#pragma unroll
  for (int i = 0; i < VPT; ++i)
    asm volatile("" : "+v"(v[i].x), "+v"(v[i].y), "+v"(v[i].z), "+v"(v[i].w));

  uint32_t rem = (uint32_t)K;
  uint32_t d1 = phase1(sh, v, rem, tid, lane, wave);

  // EARLY PROVISIONAL STORE: phase 1 classifies 97.5% of elements.
  // key>>20 > d1 -> kept; < d1 -> zero; == d1 -> provisionally kept,
  // corrected below. Fire-and-forget: drains under phases 2/3.
  const uint32_t lo = d1 << 20;
  uint4* outr = (uint4*)(out) + (size_t)row * V4;
#pragma unroll
  for (int i = 0; i < VPT; ++i) {
    uint4 o = v[i];
    o.x = ((o.x & 0x7fffffffu) >= lo) ? o.x : 0u;
    o.y = ((o.y & 0x7fffffffu) >= lo) ? o.y : 0u;
    o.z = ((o.z & 0x7fffffffu) >= lo) ? o.z : 0u;
    o.w = ((o.w & 0x7fffffffu) >= lo) ? o.w : 0u;
    outr[tid + i * TPB] = o;
  }

  uint32_t d2 = phase23(sh, v, 10, 20, d1, rem, tid, lane, wave);
  uint32_t d3 = phase23(sh, v,  0, 10, (d1 << 10) | d2, rem, tid, lane, wave);

  const uint32_t thr = (d1 << 20) | (d2 << 10) | d3;  // exact K-th largest |x| bits

  // CORRECTION: zero the pending elements with key in [lo, thr). Uniform
  // skip when thr == lo (then the provisional store was already exact).
  // The vmcnt(0) drain guarantees the provisional store of each address has
  // completed before its correction store (same thread, same address); by
  // now phases 2/3 have covered the drain latency, so the wait is cheap.
  if (thr != lo) {
    asm volatile("s_waitcnt vmcnt(0)" ::: "memory");
    uint32_t* outw = (uint32_t*)outr;
#pragma unroll
    for (int i = 0; i < VPT; ++i) {
      uint32_t a[4] = {v[i].x, v[i].y, v[i].z, v[i].w};
#pragma unroll
      for (int j = 0; j < 4; ++j) {
        uint32_t key = a[j] & 0x7fffffffu;
        if (key >= lo && key < thr)
          outw[4 * (tid + i * TPB) + j] = 0u;
      }
    }
  }
}

extern "C" void kernel_launch(void* const* d_in, const int* in_sizes, int n_in,
                              void* d_out, int out_size, void* d_ws, size_t ws_size,
                              hipStream_t stream) {
  (void)n_in; (void)out_size; (void)d_ws; (void)ws_size;
  const float* x = (const float*)d_in[0];
  float* out = (float*)d_out;
  const int rows = in_sizes[0] / NCOLS;
  const int K = (int)(0.1 * NCOLS + 0.5);  // round(819.2) = 819
  topk_row_kernel<<<rows, TPB, 0, stream>>>(x, out, K);
}

// Round 14
// 229.658 us; speedup vs baseline: 1.0418x; 1.0418x over previous
//
#include <hip/hip_runtime.h>
#include <stdint.h>

// Per-row top-K magnitude masking, exact.
// x: (4096 rows, 8192 cols) fp32. K = 819. One 256-thread block per row, row
// held in registers (8 x uint4 / thread). Exact radix select on the 31-bit
// abs bit pattern in 3 phases: 11 bits (2048 u32 bins, 2 copies), 10, 10.
//
// R14 = R13 retried byte-identical (R13's bench died on container infra,
// not the kernel; R2->R3 precedent). R13 = R6 skeleton, MACHINERY SHAVED.
// Model fitting all rounds: per-CU per-row time = HBM 6.4K + VALU 3.4K +
// DS 1.7K + barriers ~1K = 12.4K cyc (sum, no overlap: co-resident
// identical blocks lockstep through shared pipes; 6 desync structures each
// cost >= their overlap gain). So shrink the terms instead:
//  1. Phase-1 histogram UNPACKED u32 (2048 bins x 2 copies, 16.4 KB): the
//     u16 halfword packing cost ~3 VALU/elem and bought only atomic-
//     contention relief, which R9-R11 measured as irrelevant. Now
//     3 VALU/elem (and, shift, addr) -- digit t>>20 needs no mask.
//  2. Disjoint per-phase hist regions zeroed ONCE up front: kills the
//     per-phase zero pass and its barrier. 13 -> 10 barriers/row.
//  3. Phases 2/3 use subtract-compare predicates: u = t - prefix;
//     candidate iff u < range; digit = u>>10 (or u). ~2 VALU/elem cheaper.
// Everything else (scan, pick, store, load, pin) identical to R6.

constexpr int NCOLS = 8192;
constexpr int TPB   = 256;
constexpr int V4    = NCOLS / 4;   // 2048 uint4 per row
constexpr int VPT   = V4 / TPB;    // 8 uint4 per thread

constexpr int PAD = 8;
constexpr int B1  = 2048;          // phase-1 bins (u32, unpacked)
constexpr int S1w = B1 + PAD;      // 2056 words per copy
constexpr int C1  = 2;             // phase-1 copies (one per wave-pair)
constexpr int B2  = 1024;          // phase-2/3 bins
constexpr int S2w = B2 + PAD;      // 1032
constexpr int OF2 = C1 * S1w;      // 4112: phase-2 hist offset
constexpr int OF3 = OF2 + S2w;     // 5144: phase-3 hist offset
constexpr int HW  = OF3 + S2w;     // 6176 words = 24.7 KB

struct Shared {
  uint32_t hist[HW];
  uint32_t wavesum[4];
  uint32_t digit;
  uint32_t rem;
};

// Suffix-scan + winner pick. hb[] = this thread's bin counts over bins
// [tid*BPT, tid*BPT+BPT). S(b) = #candidates with digit >= b. Winner:
// S(b) >= rem && S(b+1) < rem (unique). Updates rem to rank within bin.
// 2 barriers. Safe without a trailing barrier: the next phase's
// atomics-done barrier separates these reads from the next pick's writes.
template <int BPT>
__device__ __forceinline__ uint32_t pick_winner(Shared& sh, const uint32_t (&hb)[BPT],
                                                uint32_t& rem, int tid, int lane, int wave) {
  uint32_t L = 0;
#pragma unroll
  for (int j = 0; j < BPT; ++j) L += hb[j];

  uint32_t suf = L;                        // wave inclusive suffix scan
#pragma unroll
  for (int off = 1; off < 64; off <<= 1) {
    uint32_t o = __shfl_down(suf, off, 64);
    suf += (lane + off < 64) ? o : 0u;
  }
  if (lane == 0) sh.wavesum[wave] = suf;   // wave total
  __syncthreads();
  uint32_t addw = 0;
#pragma unroll
  for (int w = 0; w < 4; ++w) addw += (w > wave) ? sh.wavesum[w] : 0u;
  suf += addw;  // suffix count starting at this thread's first bin

  uint32_t s = suf - L;                    // S at bin (tid+1)*BPT
#pragma unroll
  for (int j = BPT - 1; j >= 0; --j) {
    uint32_t snext = s;                    // S(bin+1)
    s += hb[j];                            // S(bin)
    if (s >= rem && snext < rem) {
      sh.digit = (uint32_t)(tid * BPT + j);
      sh.rem = rem - snext;
    }
  }
  __syncthreads();
  uint32_t d = sh.digit;
  rem = sh.rem;
  return d;
}

__global__ __launch_bounds__(TPB, 4) void topk_row_kernel(const float* __restrict__ x,
                                                          float* __restrict__ out,
                                                          int K) {
  __shared__ Shared sh;
  const int row  = blockIdx.x;
  const int tid  = threadIdx.x;
  const int lane = tid & 63;
  const int wave = tid >> 6;

  const uint4* xr = (const uint4*)(x) + (size_t)row * V4;
  uint4 v[VPT];
#pragma unroll
  for (int i = 0; i < VPT; ++i) v[i] = xr[tid + i * TPB];
#pragma unroll
  for (int i = 0; i < VPT; ++i)   // pin: forbid remat (proven harmless)
    asm volatile("" : "+v"(v[i].x), "+v"(v[i].y), "+v"(v[i].z), "+v"(v[i].w));

  // Zero ALL phase histograms once (they are disjoint regions).
  {
    uint4* hz = (uint4*)sh.hist;
    constexpr int ZW4 = HW / 4;            // 1544
    for (int i = tid; i < ZW4; i += TPB) hz[i] = make_uint4(0u, 0u, 0u, 0u);
  }
  __syncthreads();

  // ---- Phase 1: 11-bit digit (bits 30..20), u32 bins, 2 copies ----
  {
    uint32_t* h = &sh.hist[(wave >> 1) * S1w];
#pragma unroll
    for (int i = 0; i < VPT; ++i) {
      uint32_t a[4] = {v[i].x, v[i].y, v[i].z, v[i].w};
#pragma unroll
      for (int j = 0; j < 4; ++j) {
        uint32_t t = a[j] & 0x7fffffffu;
        atomicAdd(&h[t >> 20], 1u);        // t>>20 <= 2047: no mask needed
      }
    }
  }
  __syncthreads();

  uint32_t rem = (uint32_t)K;
  uint32_t d1;
  {
    constexpr int BPT = B1 / TPB;          // 8
    const uint4* p0 = (const uint4*)&sh.hist[0 * S1w + tid * BPT];
    const uint4* p1 = (const uint4*)&sh.hist[1 * S1w + tid * BPT];
    uint4 a0 = p0[0], a1 = p0[1], b0 = p1[0], b1 = p1[1];
    uint32_t hb[BPT] = {a0.x + b0.x, a0.y + b0.y, a0.z + b0.z, a0.w + b0.w,
                        a1.x + b1.x, a1.y + b1.y, a1.z + b1.z, a1.w + b1.w};
    d1 = pick_winner<BPT>(sh, hb, rem, tid, lane, wave);
  }

  // ---- Phase 2: 10-bit digit (bits 19..10) of the d1 bin ----
  const uint32_t lo1 = d1 << 20;
#pragma unroll
  for (int i = 0; i < VPT; ++i) {
    uint32_t a[4] = {v[i].x, v[i].y, v[i].z, v[i].w};
#pragma unroll
    for (int j = 0; j < 4; ++j) {
      uint32_t u = (a[j] & 0x7fffffffu) - lo1;
      if (u < (1u << 20))
        atomicAdd(&sh.hist[OF2 + (u >> 10)], 1u);
    }
  }
  __syncthreads();

  uint32_t d2;
  {
    constexpr int BPT = B2 / TPB;          // 4
    const uint4 t = *(const uint4*)&sh.hist[OF2 + tid * BPT];
    uint32_t hb[BPT] = {t.x, t.y, t.z, t.w};
    d2 = pick_winner<BPT>(sh, hb, rem, tid, lane, wave);
  }

  // ---- Phase 3: 10-bit digit (bits 9..0) of the (d1,d2) bin ----
  const uint32_t lo2 = lo1 | (d2 << 10);
#pragma unroll
  for (int i = 0; i < VPT; ++i) {
    uint32_t a[4] = {v[i].x, v[i].y, v[i].z, v[i].w};
#pragma unroll
    for (int j = 0; j < 4; ++j) {
      uint32_t u = (a[j] & 0x7fffffffu) - lo2;
      if (u < 1024u)
        atomicAdd(&sh.hist[OF3 + u], 1u);
    }
  }
  __syncthreads();

  uint32_t d3;
  {
    constexpr int BPT = B2 / TPB;          // 4
    const uint4 t = *(const uint4*)&sh.hist[OF3 + tid * BPT];
    uint32_t hb[BPT] = {t.x, t.y, t.z, t.w};
    d3 = pick_winner<BPT>(sh, hb, rem, tid, lane, wave);
  }

  const uint32_t thr = lo2 | d3;           // exact K-th largest |x| bits

  uint4* outr = (uint4*)(out) + (size_t)row * V4;
#pragma unroll
  for (int i = 0; i < VPT; ++i) {
    uint4 o = v[i];
    o.x = ((o.x & 0x7fffffffu) >= thr) ? o.x : 0u;
    o.y = ((o.y & 0x7fffffffu) >= thr) ? o.y : 0u;
    o.z = ((o.z & 0x7fffffffu) >= thr) ? o.z : 0u;
    o.w = ((o.w & 0x7fffffffu) >= thr) ? o.w : 0u;
    outr[tid + i * TPB] = o;
  }
}

extern "C" void kernel_launch(void* const* d_in, const int* in_sizes, int n_in,
                              void* d_out, int out_size, void* d_ws, size_t ws_size,
                              hipStream_t stream) {
  (void)n_in; (void)out_size; (void)d_ws; (void)ws_size;
  const float* x = (const float*)d_in[0];
  float* out = (float*)d_out;
  const int rows = in_sizes[0] / NCOLS;
  const int K = (int)(0.1 * NCOLS + 0.5);  // round(819.2) = 819
  topk_row_kernel<<<rows, TPB, 0, stream>>>(x, out, K);
}